// Round 3
// baseline (276.063 us; speedup 1.0000x reference)
//
#include <hip/hip_runtime.h>

// Problem constants (from setup_inputs): B=4, Nc=1024, Nf=8192, fp32.
#define B  4
#define NF 8192
#define NC 1024

// Single-node design: 1024 producer blocks + 1 reducer block.
// Producer block = (dir, b, xg): 64 x-points vs ALL 8192 y.
//   256 threads = 64 x-points x 4 y-quarters (quarter = wave id, uniform).
//   Block-local min across quarters via LDS -> sqrt -> block sum ->
//   one release-store partial per block (non-negative float).
// Reducer block: coarse L2 loss (overlapped with producers), then polls the
//   1024 partial slots. ws is poisoned 0xAA (0xAAAAAAAA: sign bit set) ->
//   natural "not ready" sentinel vs non-negative partials. Writes d_out.
// No memset, no atomicMin, ONE graph node.
#define PROD   1024
#define XPB    64            // x points per producer block
#define NSPLIT 4             // y quarters (one per wave)
#define YSEG   (NF / NSPLIT) // 2048

__global__ __launch_bounds__(256) void k_all(const float* __restrict__ rc,
                                             const float* __restrict__ rf,
                                             const float* __restrict__ gf,
                                             const float* __restrict__ gc,
                                             unsigned* __restrict__ partial,
                                             float* __restrict__ out) {
    int bx = blockIdx.x;
    int t  = threadIdx.x;
    __shared__ float sh[256];

    if (bx < PROD) {
        // decode (dir:1, b:2, xg:7)
        int dir = bx >> 9;
        int rem = bx & 511;
        int b   = rem >> 7;
        int xg  = rem & 127;

        const float* xp = dir ? gf : rf;   // x -> nearest in y
        const float* yp = dir ? rf : gf;

        int xi    = t & (XPB - 1);
        int split = t >> 6;                // == wave id, wave-uniform

        const float* xb = xp + (size_t)(b * NF + xg * XPB + xi) * 3;
        float x0 = xb[0], x1 = xb[1], x2 = xb[2];

        // y segment: offset (b*8192 + split*2048)*3 floats -> 16B aligned.
        const float4* y4 = (const float4*)(yp + (size_t)(b * NF + split * YSEG) * 3);

        float mn0 = 3.4e38f, mn1 = 3.4e38f, mn2 = 3.4e38f, mn3 = 3.4e38f;
        // 8 y-points (= 6 float4) per iteration; wave-uniform addresses.
        for (int jj = 0; jj < YSEG / 8; ++jj) {
            float4 va = y4[jj * 6 + 0];
            float4 vb = y4[jj * 6 + 1];
            float4 vc = y4[jj * 6 + 2];
            float4 vd = y4[jj * 6 + 3];
            float4 ve = y4[jj * 6 + 4];
            float4 vf = y4[jj * 6 + 5];
            float u, v, w, d0, d1, d2, d3, d4, d5, d6, d7;
            u = x0 - va.x; v = x1 - va.y; w = x2 - va.z; d0 = fmaf(u, u, fmaf(v, v, w * w));
            u = x0 - va.w; v = x1 - vb.x; w = x2 - vb.y; d1 = fmaf(u, u, fmaf(v, v, w * w));
            u = x0 - vb.z; v = x1 - vb.w; w = x2 - vc.x; d2 = fmaf(u, u, fmaf(v, v, w * w));
            u = x0 - vc.y; v = x1 - vc.z; w = x2 - vc.w; d3 = fmaf(u, u, fmaf(v, v, w * w));
            u = x0 - vd.x; v = x1 - vd.y; w = x2 - vd.z; d4 = fmaf(u, u, fmaf(v, v, w * w));
            u = x0 - vd.w; v = x1 - ve.x; w = x2 - ve.y; d5 = fmaf(u, u, fmaf(v, v, w * w));
            u = x0 - ve.z; v = x1 - ve.w; w = x2 - vf.x; d6 = fmaf(u, u, fmaf(v, v, w * w));
            u = x0 - vf.y; v = x1 - vf.z; w = x2 - vf.w; d7 = fmaf(u, u, fmaf(v, v, w * w));
            mn0 = fminf(fminf(d0, d1), mn0);   // -> v_min3_f32
            mn1 = fminf(fminf(d2, d3), mn1);
            mn2 = fminf(fminf(d4, d5), mn2);
            mn3 = fminf(fminf(d6, d7), mn3);
        }
        sh[t] = fminf(fminf(mn0, mn1), fminf(mn2, mn3));
        __syncthreads();

        if (t < XPB) {  // exactly wave 0
            float m = fminf(fminf(sh[t], sh[t + 64]), fminf(sh[t + 128], sh[t + 192]));
            float vv = sqrtf(fmaxf(m, 0.0f));
#pragma unroll
            for (int off = 32; off > 0; off >>= 1) vv += __shfl_down(vv, off);
            if (t == 0)
                __hip_atomic_store(&partial[bx], __float_as_uint(vv),
                                   __ATOMIC_RELEASE, __HIP_MEMORY_SCOPE_AGENT);
        }
    } else {
        // ---- reducer block ----
        // Coarse L2 loss first (runs while producers crunch).
        float s_crs = 0.0f;
        for (int i = t; i < B * NC; i += 256) {
            float dx = rc[3 * i + 0] - gc[3 * i + 0];
            float dy = rc[3 * i + 1] - gc[3 * i + 1];
            float dz = rc[3 * i + 2] - gc[3 * i + 2];
            s_crs += sqrtf(fmaf(dx, dx, fmaf(dy, dy, dz * dz)));
        }
        // Poll fine partials: sign bit set = not-yet-written (0xAA poison).
        float s_fin = 0.0f;
        for (int i = t; i < PROD; i += 256) {
            unsigned u;
            do {
                u = __hip_atomic_load(&partial[i], __ATOMIC_ACQUIRE,
                                      __HIP_MEMORY_SCOPE_AGENT);
            } while (u >> 31);
            s_fin += __uint_as_float(u);
        }
#pragma unroll
        for (int off = 32; off > 0; off >>= 1) {
            s_crs += __shfl_down(s_crs, off);
            s_fin += __shfl_down(s_fin, off);
        }
        int lane = t & 63, wv = t >> 6;
        if (lane == 0) { sh[wv] = s_crs; sh[4 + wv] = s_fin; }
        __syncthreads();
        if (t == 0) {
            float c = sh[0] + sh[1] + sh[2] + sh[3];
            float f = sh[4] + sh[5] + sh[6] + sh[7];
            out[0] = c * (1.0f / (float)(B * NC));        // loss_coarse
            out[1] = f * (0.5f / (float)(B * NF));        // loss_fine
        }
    }
}

extern "C" void kernel_launch(void* const* d_in, const int* in_sizes, int n_in,
                              void* d_out, int out_size, void* d_ws, size_t ws_size,
                              hipStream_t stream) {
    const float* rc = (const float*)d_in[0];  // ret_coarse [4,1024,3]
    const float* rf = (const float*)d_in[1];  // ret_fine   [4,8192,3]
    const float* gf = (const float*)d_in[2];  // gt_fine    [4,8192,3]
    const float* gc = (const float*)d_in[3];  // gt_coarse  [4,1024,3]

    unsigned* partial = (unsigned*)d_ws;      // 1024 slots, 0xAA-poisoned = sentinel
    float*    out     = (float*)d_out;

    k_all<<<PROD + 1, 256, 0, stream>>>(rc, rf, gf, gc, partial, out);
}

// Round 4
// 115.040 us; speedup vs baseline: 2.3997x; 2.3997x over previous
//
#include <hip/hip_runtime.h>

// Problem constants (from setup_inputs): B=4, Nc=1024, Nf=8192, fp32.
#define B  4
#define NF 8192
#define NC 1024

// Chamfer tiling (round-2 structure, packed-fp32 hot loop):
// 256 threads/block, K=16 x-points per thread (XC=4096).
// y staged in LDS in chunks of YC=128, TRANSPOSED into float2-pair form:
//   q0[p] = (y[2p].x, y[2p+1].x, y[2p].y, y[2p+1].y)
//   q1[p] = (y[2p].z, y[2p+1].z, |y[2p]|^2, |y[2p+1]|^2)
// Hot loop per 2 y-points per x: 3 v_pk_fma_f32 + 1 v_pk_add_f32 + 1 v_min3
// = 2.5 instruction-slots per pair (vs 4.5 scalar).
#define K  16
#define XC (K * 256)    // 4096
#define NXC (NF / XC)   // 2
#define YC 128
#define NYC (NF / YC)   // 64

#define NMIN (2 * B * NF)   // 65536 per-point NN-min slots (both directions)
#define NCRS (B * NC)       // 4096 coarse points
#define NTOT (NMIN + NCRS)

typedef float f2 __attribute__((ext_vector_type(2)));

// dir 0: x = ret_fine, y = gt_fine  (d1: each ret point -> nearest gt)
// dir 1: x = gt_fine,  y = ret_fine (d2: each gt point -> nearest ret)
__global__ __launch_bounds__(256) void k_chamfer(const float* __restrict__ rf,
                                                 const float* __restrict__ gf,
                                                 unsigned* __restrict__ minbuf) {
    __shared__ float4 q0[YC / 2];   // (x0a, x0b, y0a, y0b)
    __shared__ float4 q1[YC / 2];   // (z0a, z0b, w0a, w0b)

    int bx   = blockIdx.x;          // 1024 blocks total
    int dir  = bx >> 9;             // 512 blocks per direction
    int rem  = bx & 511;
    int b    = rem >> 7;            // 128 blocks per batch
    int rem2 = rem & 127;
    int xi   = rem2 >> 6;           // 2 x-chunks
    int yj   = rem2 & 63;           // 64 y-chunks

    const float* xp = dir ? gf : rf;
    const float* yp = dir ? rf : gf;
    int t = threadIdx.x;

    // Stage y chunk -> LDS, transposed into packed-pair layout.
    const float* yb = yp + (size_t)(b * NF + yj * YC) * 3;
    if (t < YC / 2) {
        float a0 = yb[6 * t + 0], a1 = yb[6 * t + 1], a2 = yb[6 * t + 2];
        float b0 = yb[6 * t + 3], b1 = yb[6 * t + 4], b2 = yb[6 * t + 5];
        float wa = fmaf(a0, a0, fmaf(a1, a1, a2 * a2));
        float wb = fmaf(b0, b0, fmaf(b1, b1, b2 * b2));
        q0[t] = make_float4(a0, b0, a1, b1);
        q1[t] = make_float4(a2, b2, wa, wb);
    }

    // Per-thread x points: precompute m = -2x and c = |x|^2
    const float* xb = xp + (size_t)(b * NF + xi * XC) * 3;
    float m0[K], m1[K], m2[K], cc[K], mn[K];
#pragma unroll
    for (int k = 0; k < K; ++k) {
        int i = k * 256 + t;
        float x0 = xb[3 * i + 0], x1 = xb[3 * i + 1], x2 = xb[3 * i + 2];
        m0[k] = -2.0f * x0;
        m1[k] = -2.0f * x1;
        m2[k] = -2.0f * x2;
        cc[k] = fmaf(x0, x0, fmaf(x1, x1, x2 * x2));
        mn[k] = 3.4e38f;
    }
    __syncthreads();

    // Hot loop: 2 broadcast ds_read_b128 + K x (3 pk_fma + 1 pk_add + 1 min3)
#pragma unroll 2
    for (int p = 0; p < YC / 2; ++p) {
        float4 a = q0[p];
        float4 c = q1[p];
        f2 X = {a.x, a.y};
        f2 Y = {a.z, a.w};
        f2 Z = {c.x, c.y};
        f2 W = {c.z, c.w};
#pragma unroll
        for (int k = 0; k < K; ++k) {
            f2 D = __builtin_elementwise_fma((f2){m0[k], m0[k]}, X, (f2){cc[k], cc[k]});
            D = __builtin_elementwise_fma((f2){m1[k], m1[k]}, Y, D);
            D = __builtin_elementwise_fma((f2){m2[k], m2[k]}, Z, D);
            D = D + W;                                   // v_pk_add_f32
            mn[k] = fminf(fminf(D.x, D.y), mn[k]);       // v_min3_f32
        }
    }

    // Combine partial mins across y-chunks: uint atomicMin is order-correct
    // for non-negative IEEE floats (clamp the tiny negative cancellation).
    unsigned* mb = minbuf + dir * (B * NF) + b * NF + xi * XC;
#pragma unroll
    for (int k = 0; k < K; ++k) {
        float v = fmaxf(mn[k], 0.0f);
        atomicMin(&mb[k * 256 + t], __float_as_uint(v));
    }
}

__global__ __launch_bounds__(256) void k_reduce(const unsigned* __restrict__ minbuf,
                                                const float* __restrict__ rc,
                                                const float* __restrict__ gc,
                                                float* __restrict__ out) {
    float s_crs = 0.f, s_fine = 0.f;
    for (int i = blockIdx.x * 256 + threadIdx.x; i < NTOT; i += gridDim.x * 256) {
        if (i < NMIN) {
            s_fine += sqrtf(__uint_as_float(minbuf[i]));
        } else {
            int p = i - NMIN;
            float dx = rc[3 * p + 0] - gc[3 * p + 0];
            float dy = rc[3 * p + 1] - gc[3 * p + 1];
            float dz = rc[3 * p + 2] - gc[3 * p + 2];
            s_crs += sqrtf(fmaf(dx, dx, fmaf(dy, dy, dz * dz)));
        }
    }
    // wave64 shuffle reduction
#pragma unroll
    for (int off = 32; off > 0; off >>= 1) {
        s_crs  += __shfl_down(s_crs, off);
        s_fine += __shfl_down(s_fine, off);
    }
    __shared__ float red[2][4];
    int lane = threadIdx.x & 63, w = threadIdx.x >> 6;
    if (lane == 0) { red[0][w] = s_crs; red[1][w] = s_fine; }
    __syncthreads();
    if (threadIdx.x == 0) {
        float t0 = red[0][0] + red[0][1] + red[0][2] + red[0][3];
        float t1 = red[1][0] + red[1][1] + red[1][2] + red[1][3];
        atomicAdd(&out[0], t0 * (1.0f / (float)NCRS));     // loss_coarse
        atomicAdd(&out[1], t1 * (0.5f / (float)(B * NF))); // loss_fine
    }
}

extern "C" void kernel_launch(void* const* d_in, const int* in_sizes, int n_in,
                              void* d_out, int out_size, void* d_ws, size_t ws_size,
                              hipStream_t stream) {
    const float* rc = (const float*)d_in[0];  // ret_coarse [4,1024,3]
    const float* rf = (const float*)d_in[1];  // ret_fine   [4,8192,3]
    const float* gf = (const float*)d_in[2];  // gt_fine    [4,8192,3]
    const float* gc = (const float*)d_in[3];  // gt_coarse  [4,1024,3]

    unsigned* minbuf = (unsigned*)d_ws;
    float*    out    = (float*)d_out;

    // 0xFFFFFFFF = uint max -> atomicMin sentinel; memset nodes are
    // graph-capturable and overhead is fixed regardless of node count.
    hipMemsetAsync(minbuf, 0xFF, (size_t)NMIN * sizeof(unsigned), stream);
    hipMemsetAsync(out, 0, 2 * sizeof(float), stream);

    k_chamfer<<<2 * B * NXC * NYC, 256, 0, stream>>>(rf, gf, minbuf);
    k_reduce<<<64, 256, 0, stream>>>(minbuf, rc, gc, out);
}